// Round 3
// baseline (507.027 us; speedup 1.0000x reference)
//
#include <hip/hip_runtime.h>
#include <hip/hip_bf16.h>
#include <math.h>

#define NTOK 32768
#define HID  1024
#define NEXP 64
#define H4   256

typedef __attribute__((ext_vector_type(8))) short bf16x8;
typedef __attribute__((ext_vector_type(4))) float f32x4;

static __device__ __forceinline__ ushort f2bf(float x) {
    unsigned u = __float_as_uint(x);
    unsigned r = (u + 0x7FFFu + ((u >> 16) & 1u)) >> 16;   // RNE
    return (ushort)r;
}

// ---------------------------------------------------------------------------
// Kernel 0: pre-split w1 into bf16 hi/lo, K-panel layout [p][col][32]
// ---------------------------------------------------------------------------
__global__ __launch_bounds__(256) void prep_w1(const float* __restrict__ W1,
                                               ushort* __restrict__ W1h,
                                               ushort* __restrict__ W1l)
{
    const int id = blockIdx.x * 256 + threadIdx.x;
    const int c  = id >> 8;
    const int kc = id & 255;
    const int k0 = kc * 4;
    const float4 v = *(const float4*)(W1 + (size_t)c * HID + k0);
    const int p  = k0 >> 5;
    const int kk = k0 & 31;
    const size_t dst = ((size_t)p * H4 + c) * 32 + kk;
    const float xs[4] = {v.x, v.y, v.z, v.w};
    ushort hv[4], lv[4];
#pragma unroll
    for (int j = 0; j < 4; j++) {
        const ushort h = f2bf(xs[j]);
        hv[j] = h;
        lv[j] = f2bf(xs[j] - __uint_as_float(((unsigned)h) << 16));
    }
    *(ushort4*)(W1h + dst) = make_ushort4(hv[0], hv[1], hv[2], hv[3]);
    *(ushort4*)(W1l + dst) = make_ushort4(lv[0], lv[1], lv[2], lv[3]);
}

// ---------------------------------------------------------------------------
// Kernel 1: exact fp32 router-logits GEMM, K-split x4 for occupancy.
// grid (256, 4): blockIdx.y = K-chunk of 256. atomicAdd epilogue.
// ---------------------------------------------------------------------------
__global__ __launch_bounds__(256) void logits_gemm(
    const float* __restrict__ X, const float* __restrict__ RW,
    float* __restrict__ logits)
{
    const int tid   = threadIdx.x;
    const int tok0  = blockIdx.x * 128;
    const int kbase = blockIdx.y * 256;

    __shared__ float Xs[16][128];
    __shared__ float Ws[16][64];

    float acc[4][8];
#pragma unroll
    for (int i = 0; i < 4; i++)
#pragma unroll
        for (int j = 0; j < 8; j++) acc[i][j] = 0.f;

    const int tg = tid & 31;
    const int og = tid >> 5;

    for (int kt = 0; kt < 16; kt++) {
        const int k0 = kbase + kt * 16;
#pragma unroll
        for (int r = 0; r < 2; r++) {
            int idx = tid + r * 256;
            int tl = idx & 127, kg = idx >> 7;
            const float4 v = *(const float4*)(X + (size_t)(tok0 + tl) * HID + k0 + kg * 4);
            Xs[kg * 4 + 0][tl] = v.x; Xs[kg * 4 + 1][tl] = v.y;
            Xs[kg * 4 + 2][tl] = v.z; Xs[kg * 4 + 3][tl] = v.w;
        }
        {
            int ml = tid & 63, kg = tid >> 6;
            const float4 v = *(const float4*)(RW + (size_t)ml * HID + k0 + kg * 4);
            Ws[kg * 4 + 0][ml] = v.x; Ws[kg * 4 + 1][ml] = v.y;
            Ws[kg * 4 + 2][ml] = v.z; Ws[kg * 4 + 3][ml] = v.w;
        }
        __syncthreads();
#pragma unroll
        for (int kk = 0; kk < 16; kk++) {
            const float4 xv = *(const float4*)&Xs[kk][tg * 4];
            const float4 wa = *(const float4*)&Ws[kk][og * 8];
            const float4 wb = *(const float4*)&Ws[kk][og * 8 + 4];
            const float xr[4] = {xv.x, xv.y, xv.z, xv.w};
            const float wr[8] = {wa.x, wa.y, wa.z, wa.w, wb.x, wb.y, wb.z, wb.w};
#pragma unroll
            for (int i = 0; i < 4; i++)
#pragma unroll
                for (int j = 0; j < 8; j++) acc[i][j] += xr[i] * wr[j];
        }
        __syncthreads();
    }

#pragma unroll
    for (int i = 0; i < 4; i++) {
        const int tok = tok0 + tg * 4 + i;
        float* lp = logits + (size_t)tok * NEXP + og * 8;
#pragma unroll
        for (int j = 0; j < 8; j++) atomicAdd(lp + j, acc[i][j]);
    }
}

// ---------------------------------------------------------------------------
// Kernel 2: complexity predictor via split-bf16 MFMA (unchanged from R2).
// ---------------------------------------------------------------------------
__global__ __launch_bounds__(256) void pred_mfma(
    const float* __restrict__ X,
    const ushort* __restrict__ W1h, const ushort* __restrict__ W1l,
    const float* __restrict__ B1, const float* __restrict__ W2,
    float* __restrict__ s2ws)
{
    __shared__ ushort Ah[4096];
    __shared__ ushort Al[4096];
    __shared__ ushort Bh[4096];
    __shared__ ushort Bl[4096];

    const int tid  = threadIdx.x;
    const int lane = tid & 63;
    const int wave = tid >> 6;
    const int wr = wave >> 1, wc = wave & 1;
    const int quad = lane >> 4, l15 = lane & 15;
    const int tok0 = blockIdx.x * 128;
    const int cb   = blockIdx.y;

    f32x4 acc[4][4];
#pragma unroll
    for (int fi = 0; fi < 4; fi++)
#pragma unroll
        for (int fj = 0; fj < 4; fj++) acc[fi][fj] = (f32x4){0.f, 0.f, 0.f, 0.f};

    float w2r[4], b1r[4];
#pragma unroll
    for (int f = 0; f < 4; f++) {
        const int col = cb * 128 + wc * 64 + f * 16 + l15;
        w2r[f] = W2[col];
        b1r[f] = B1[col];
    }

    for (int p = 0; p < 32; ++p) {
        const int k0 = p * 32;
        __syncthreads();

        {
            const size_t tile = ((size_t)p * H4 + cb * 128) * 32;
#pragma unroll
            for (int i = 0; i < 2; ++i) {
                const int j = i * 256 + tid;
                __builtin_amdgcn_global_load_lds(
                    (const __attribute__((address_space(1))) void*)(W1h + tile + (size_t)j * 8),
                    (__attribute__((address_space(3))) void*)((char*)Bh + (size_t)j * 16),
                    16, 0, 0);
                __builtin_amdgcn_global_load_lds(
                    (const __attribute__((address_space(1))) void*)(W1l + tile + (size_t)j * 8),
                    (__attribute__((address_space(3))) void*)((char*)Bl + (size_t)j * 16),
                    16, 0, 0);
            }
        }

#pragma unroll
        for (int it = 0; it < 4; ++it) {
            const int idx = it * 256 + tid;
            const int t   = idx >> 3;
            const int kc  = idx & 7;
            const float4 v = *(const float4*)(X + (size_t)(tok0 + t) * HID + k0 + kc * 4);
            const float xs[4] = {v.x, v.y, v.z, v.w};
            ushort hv[4], lv[4];
#pragma unroll
            for (int j = 0; j < 4; j++) {
                const ushort h = f2bf(xs[j]);
                hv[j] = h;
                lv[j] = f2bf(xs[j] - __uint_as_float(((unsigned)h) << 16));
            }
            const int a = t * 32 + kc * 4;
            *(ushort4*)&Ah[a] = make_ushort4(hv[0], hv[1], hv[2], hv[3]);
            *(ushort4*)&Al[a] = make_ushort4(lv[0], lv[1], lv[2], lv[3]);
        }
        __syncthreads();

        bf16x8 a_h[4], a_l[4], b_h[4], b_l[4];
#pragma unroll
        for (int f = 0; f < 4; ++f) {
            const int ra = (wr * 64 + f * 16 + l15) * 32 + quad * 8;
            const int rb = (wc * 64 + f * 16 + l15) * 32 + quad * 8;
            a_h[f] = *(const bf16x8*)&Ah[ra];
            a_l[f] = *(const bf16x8*)&Al[ra];
            b_h[f] = *(const bf16x8*)&Bh[rb];
            b_l[f] = *(const bf16x8*)&Bl[rb];
        }
#pragma unroll
        for (int fi = 0; fi < 4; ++fi)
#pragma unroll
            for (int fj = 0; fj < 4; ++fj) {
                acc[fi][fj] = __builtin_amdgcn_mfma_f32_16x16x32_bf16(a_h[fi], b_h[fj], acc[fi][fj], 0, 0, 0);
                acc[fi][fj] = __builtin_amdgcn_mfma_f32_16x16x32_bf16(a_l[fi], b_h[fj], acc[fi][fj], 0, 0, 0);
                acc[fi][fj] = __builtin_amdgcn_mfma_f32_16x16x32_bf16(a_h[fi], b_l[fj], acc[fi][fj], 0, 0, 0);
            }
    }

#pragma unroll
    for (int fi = 0; fi < 4; ++fi) {
#pragma unroll
        for (int r = 0; r < 4; ++r) {
            float s = 0.f;
#pragma unroll
            for (int fj = 0; fj < 4; ++fj) {
                const float hval = acc[fi][fj][r] + b1r[fj];
                s = fmaf(w2r[fj], fmaxf(hval, 0.f), s);
            }
            s += __shfl_xor(s, 1);
            s += __shfl_xor(s, 2);
            s += __shfl_xor(s, 4);
            s += __shfl_xor(s, 8);
            if (l15 == 0)
                atomicAdd(&s2ws[tok0 + wr * 64 + fi * 16 + quad * 4 + r], s);
        }
    }
}

// ---------------------------------------------------------------------------
// Kernel 3: per-token routing v2 — no LDS atomics, no per-expert logf.
// One wave (64 thr) per block, 1 token per lane, grid 512.
//   entropy = log S - (sum e^z * z)/S   (1e-8 term ~6e-7, negligible)
//   expert_load: per-expert wave butterfly, one global atomic per lane.
// ---------------------------------------------------------------------------
__global__ __launch_bounds__(64) void route_kernel(
    const float* __restrict__ logits, const float* __restrict__ s2ws,
    const float* __restrict__ B2, float* __restrict__ sel,
    float* __restrict__ wts, float* __restrict__ load_sum,
    float* __restrict__ ent_sum)
{
    const int lane = threadIdx.x;           // 0..63
    const int tok  = blockIdx.x * 64 + lane;

    float r[64];
    const float* lr = logits + (size_t)tok * NEXP;
#pragma unroll
    for (int e4 = 0; e4 < 16; e4++) {
        float4 v = *(const float4*)(lr + e4 * 4);
        r[e4 * 4 + 0] = v.x; r[e4 * 4 + 1] = v.y;
        r[e4 * 4 + 2] = v.z; r[e4 * 4 + 3] = v.w;
    }

    // top-4, strict > keeps earliest index on ties (matches lax.top_k)
    float v0 = -1e30f, v1 = -1e30f, v2 = -1e30f, v3 = -1e30f;
    int   i0 = 0, i1 = 0, i2 = 0, i3 = 0;
#pragma unroll
    for (int e = 0; e < 64; e++) {
        const float v = r[e];
        if (v > v3) {
            if (v > v2) {
                if (v > v1) {
                    if (v > v0) { v3=v2;i3=i2; v2=v1;i2=i1; v1=v0;i1=i0; v0=v;i0=e; }
                    else        { v3=v2;i3=i2; v2=v1;i2=i1; v1=v;i1=e; }
                } else          { v3=v2;i3=i2; v2=v;i2=e; }
            } else              { v3=v;i3=e; }
        }
    }

    const float s2 = s2ws[tok] + B2[0];
    const bool k4 = (s2 > 0.f);

    float w0, w1v, w2v, w3v;
    int   s1i, s2i, s3i;
    if (k4) {
        const float e0 = expf(v0 - v0), e1 = expf(v1 - v0);
        const float e2 = expf(v2 - v0), e3 = expf(v3 - v0);
        const float inv4 = 1.f / (e0 + e1 + e2 + e3);
        w0 = e0 * inv4; w1v = e1 * inv4; w2v = e2 * inv4; w3v = e3 * inv4;
        s1i = i1; s2i = i2; s3i = i3;
    } else {
        w0 = 1.f; w1v = 0.f; w2v = 0.f; w3v = 0.f;
        s1i = 0; s2i = 0; s3i = 0;
    }
    {
        float4 sv = {(float)i0, (float)s1i, (float)s2i, (float)s3i};
        float4 wv = {w0, w1v, w2v, w3v};
        *(float4*)(sel + (size_t)tok * 4) = sv;
        *(float4*)(wts + (size_t)tok * 4) = wv;
    }

    // softmax stats
    const float mx = v0;
    float S = 0.f, pz = 0.f;
#pragma unroll
    for (int e = 0; e < 64; e++) {
        const float z = r[e] - mx;
        const float t = expf(z);
        S += t; pz = fmaf(t, z, pz);
        r[e] = t;
    }
    const float inv = 1.f / S;
    float ent = logf(S) - pz * inv;

    // expert-load: butterfly-sum p[e] across the wave; lane e keeps expert e
    float myload = 0.f;
#pragma unroll
    for (int e = 0; e < 64; e++) {
        float s = r[e] * inv;
        s += __shfl_xor(s, 1);
        s += __shfl_xor(s, 2);
        s += __shfl_xor(s, 4);
        s += __shfl_xor(s, 8);
        s += __shfl_xor(s, 16);
        s += __shfl_xor(s, 32);
        if (lane == e) myload = s;
    }
    atomicAdd(&load_sum[lane], myload);

    ent += __shfl_xor(ent, 1);
    ent += __shfl_xor(ent, 2);
    ent += __shfl_xor(ent, 4);
    ent += __shfl_xor(ent, 8);
    ent += __shfl_xor(ent, 16);
    ent += __shfl_xor(ent, 32);
    if (lane == 0) atomicAdd(ent_sum, ent);
}

__global__ void finalize_kernel(const float* __restrict__ load_sum,
                                const float* __restrict__ ent_sum,
                                float* __restrict__ out_scal)
{
    const int lane = threadIdx.x;
    const float le = load_sum[lane] * (1.f / (float)NTOK);
    float s = le;
#pragma unroll
    for (int o = 32; o >= 1; o >>= 1) s += __shfl_xor(s, o);
    const float mean = s * (1.f / 64.f);
    const float d = le - mean;
    float v = d * d;
#pragma unroll
    for (int o = 32; o >= 1; o >>= 1) v += __shfl_xor(v, o);
    if (lane == 0) {
        out_scal[0] = v * (1.f / 63.f);
        out_scal[1] = ent_sum[0] * (1.f / (float)NTOK);
    }
}

extern "C" void kernel_launch(void* const* d_in, const int* in_sizes, int n_in,
                              void* d_out, int out_size, void* d_ws, size_t ws_size,
                              hipStream_t stream) {
    const float* X  = (const float*)d_in[0];
    const float* RW = (const float*)d_in[1];
    const float* W1 = (const float*)d_in[2];
    const float* B1 = (const float*)d_in[3];
    const float* W2 = (const float*)d_in[4];
    const float* B2 = (const float*)d_in[5];

    float* out    = (float*)d_out;
    float* logits = out;
    float* sel    = out + (size_t)NTOK * NEXP;
    float* wts    = sel + (size_t)NTOK * 4;
    float* scal   = wts + (size_t)NTOK * 4;

    float* s2ws     = (float*)d_ws;
    float* load_sum = s2ws + NTOK;
    float* ent_sum  = load_sum + 64;
    ushort* W1h = (ushort*)(s2ws + NTOK + 256);
    ushort* W1l = W1h + (size_t)H4 * HID;

    hipMemsetAsync(d_ws, 0, (size_t)(NTOK + 65) * sizeof(float), stream);
    hipMemsetAsync(logits, 0, (size_t)NTOK * NEXP * sizeof(float), stream);

    prep_w1<<<256, 256, 0, stream>>>(W1, W1h, W1l);
    logits_gemm<<<dim3(NTOK / 128, 4), 256, 0, stream>>>(X, RW, logits);
    pred_mfma<<<dim3(NTOK / 128, 2), 256, 0, stream>>>(X, W1h, W1l, B1, W2, s2ws);
    route_kernel<<<NTOK / 64, 64, 0, stream>>>(logits, s2ws, B2, sel, wts, load_sum, ent_sum);
    finalize_kernel<<<1, 64, 0, stream>>>(load_sum, ent_sum, scal);
}

// Round 4
// 343.013 us; speedup vs baseline: 1.4782x; 1.4782x over previous
//
#include <hip/hip_runtime.h>
#include <hip/hip_bf16.h>
#include <math.h>

#define NTOK 32768
#define HID  1024
#define NEXP 64
#define H4   256

typedef __attribute__((ext_vector_type(8))) short bf16x8;
typedef __attribute__((ext_vector_type(4))) float f32x4;

static __device__ __forceinline__ ushort f2bf(float x) {
    unsigned u = __float_as_uint(x);
    unsigned r = (u + 0x7FFFu + ((u >> 16) & 1u)) >> 16;   // RNE
    return (ushort)r;
}

// ---------------------------------------------------------------------------
// Kernel 0: pre-split w1 into bf16 hi/lo, K-panel layout [p][col][32]
// ---------------------------------------------------------------------------
__global__ __launch_bounds__(256) void prep_w1(const float* __restrict__ W1,
                                               ushort* __restrict__ W1h,
                                               ushort* __restrict__ W1l)
{
    const int id = blockIdx.x * 256 + threadIdx.x;
    const int c  = id >> 8;
    const int kc = id & 255;
    const int k0 = kc * 4;
    const float4 v = *(const float4*)(W1 + (size_t)c * HID + k0);
    const int p  = k0 >> 5;
    const int kk = k0 & 31;
    const size_t dst = ((size_t)p * H4 + c) * 32 + kk;
    const float xs[4] = {v.x, v.y, v.z, v.w};
    ushort hv[4], lv[4];
#pragma unroll
    for (int j = 0; j < 4; j++) {
        const ushort h = f2bf(xs[j]);
        hv[j] = h;
        lv[j] = f2bf(xs[j] - __uint_as_float(((unsigned)h) << 16));
    }
    *(ushort4*)(W1h + dst) = make_ushort4(hv[0], hv[1], hv[2], hv[3]);
    *(ushort4*)(W1l + dst) = make_ushort4(lv[0], lv[1], lv[2], lv[3]);
}

// ---------------------------------------------------------------------------
// Kernel 1: exact fp32 router-logits GEMM v3.
// Full K per block (no atomics), 64 tok x 64 col tile -> grid 512 for
// occupancy, 4x4 thread tile, direct float4 stores.
// ---------------------------------------------------------------------------
__global__ __launch_bounds__(256) void logits_gemm(
    const float* __restrict__ X, const float* __restrict__ RW,
    float* __restrict__ logits)
{
    const int tid  = threadIdx.x;
    const int tok0 = blockIdx.x * 64;

    __shared__ float Xs[16][64];
    __shared__ float Ws[16][64];

    float acc[4][4];
#pragma unroll
    for (int i = 0; i < 4; i++)
#pragma unroll
        for (int j = 0; j < 4; j++) acc[i][j] = 0.f;

    const int tg = tid & 15;    // token group: tokens tg*4 .. tg*4+3
    const int og = tid >> 4;    // col group:   cols   og*4 .. og*4+3
    const int st = tid >> 2;    // staging row (token or expert)
    const int kg = tid & 3;     // staging k-chunk

    for (int k0 = 0; k0 < HID; k0 += 16) {
        {
            const float4 v = *(const float4*)(X + (size_t)(tok0 + st) * HID + k0 + kg * 4);
            Xs[kg * 4 + 0][st] = v.x; Xs[kg * 4 + 1][st] = v.y;
            Xs[kg * 4 + 2][st] = v.z; Xs[kg * 4 + 3][st] = v.w;
        }
        {
            const float4 v = *(const float4*)(RW + (size_t)st * HID + k0 + kg * 4);
            Ws[kg * 4 + 0][st] = v.x; Ws[kg * 4 + 1][st] = v.y;
            Ws[kg * 4 + 2][st] = v.z; Ws[kg * 4 + 3][st] = v.w;
        }
        __syncthreads();
#pragma unroll
        for (int kk = 0; kk < 16; kk++) {
            const float4 xv = *(const float4*)&Xs[kk][tg * 4];
            const float4 wv = *(const float4*)&Ws[kk][og * 4];
            const float xr[4] = {xv.x, xv.y, xv.z, xv.w};
            const float wr[4] = {wv.x, wv.y, wv.z, wv.w};
#pragma unroll
            for (int i = 0; i < 4; i++)
#pragma unroll
                for (int j = 0; j < 4; j++) acc[i][j] += xr[i] * wr[j];
        }
        __syncthreads();
    }

#pragma unroll
    for (int i = 0; i < 4; i++) {
        const int tok = tok0 + tg * 4 + i;
        float4 a = {acc[i][0], acc[i][1], acc[i][2], acc[i][3]};
        *(float4*)(logits + (size_t)tok * NEXP + og * 4) = a;
    }
}

// ---------------------------------------------------------------------------
// Kernel 2: complexity predictor via split-bf16 MFMA (unchanged, proven).
// ---------------------------------------------------------------------------
__global__ __launch_bounds__(256) void pred_mfma(
    const float* __restrict__ X,
    const ushort* __restrict__ W1h, const ushort* __restrict__ W1l,
    const float* __restrict__ B1, const float* __restrict__ W2,
    float* __restrict__ s2ws)
{
    __shared__ ushort Ah[4096];
    __shared__ ushort Al[4096];
    __shared__ ushort Bh[4096];
    __shared__ ushort Bl[4096];

    const int tid  = threadIdx.x;
    const int lane = tid & 63;
    const int wave = tid >> 6;
    const int wr = wave >> 1, wc = wave & 1;
    const int quad = lane >> 4, l15 = lane & 15;
    const int tok0 = blockIdx.x * 128;
    const int cb   = blockIdx.y;

    f32x4 acc[4][4];
#pragma unroll
    for (int fi = 0; fi < 4; fi++)
#pragma unroll
        for (int fj = 0; fj < 4; fj++) acc[fi][fj] = (f32x4){0.f, 0.f, 0.f, 0.f};

    float w2r[4], b1r[4];
#pragma unroll
    for (int f = 0; f < 4; f++) {
        const int col = cb * 128 + wc * 64 + f * 16 + l15;
        w2r[f] = W2[col];
        b1r[f] = B1[col];
    }

    for (int p = 0; p < 32; ++p) {
        const int k0 = p * 32;
        __syncthreads();

        {
            const size_t tile = ((size_t)p * H4 + cb * 128) * 32;
#pragma unroll
            for (int i = 0; i < 2; ++i) {
                const int j = i * 256 + tid;
                __builtin_amdgcn_global_load_lds(
                    (const __attribute__((address_space(1))) void*)(W1h + tile + (size_t)j * 8),
                    (__attribute__((address_space(3))) void*)((char*)Bh + (size_t)j * 16),
                    16, 0, 0);
                __builtin_amdgcn_global_load_lds(
                    (const __attribute__((address_space(1))) void*)(W1l + tile + (size_t)j * 8),
                    (__attribute__((address_space(3))) void*)((char*)Bl + (size_t)j * 16),
                    16, 0, 0);
            }
        }

#pragma unroll
        for (int it = 0; it < 4; ++it) {
            const int idx = it * 256 + tid;
            const int t   = idx >> 3;
            const int kc  = idx & 7;
            const float4 v = *(const float4*)(X + (size_t)(tok0 + t) * HID + k0 + kc * 4);
            const float xs[4] = {v.x, v.y, v.z, v.w};
            ushort hv[4], lv[4];
#pragma unroll
            for (int j = 0; j < 4; j++) {
                const ushort h = f2bf(xs[j]);
                hv[j] = h;
                lv[j] = f2bf(xs[j] - __uint_as_float(((unsigned)h) << 16));
            }
            const int a = t * 32 + kc * 4;
            *(ushort4*)&Ah[a] = make_ushort4(hv[0], hv[1], hv[2], hv[3]);
            *(ushort4*)&Al[a] = make_ushort4(lv[0], lv[1], lv[2], lv[3]);
        }
        __syncthreads();

        bf16x8 a_h[4], a_l[4], b_h[4], b_l[4];
#pragma unroll
        for (int f = 0; f < 4; ++f) {
            const int ra = (wr * 64 + f * 16 + l15) * 32 + quad * 8;
            const int rb = (wc * 64 + f * 16 + l15) * 32 + quad * 8;
            a_h[f] = *(const bf16x8*)&Ah[ra];
            a_l[f] = *(const bf16x8*)&Al[ra];
            b_h[f] = *(const bf16x8*)&Bh[rb];
            b_l[f] = *(const bf16x8*)&Bl[rb];
        }
#pragma unroll
        for (int fi = 0; fi < 4; ++fi)
#pragma unroll
            for (int fj = 0; fj < 4; ++fj) {
                acc[fi][fj] = __builtin_amdgcn_mfma_f32_16x16x32_bf16(a_h[fi], b_h[fj], acc[fi][fj], 0, 0, 0);
                acc[fi][fj] = __builtin_amdgcn_mfma_f32_16x16x32_bf16(a_l[fi], b_h[fj], acc[fi][fj], 0, 0, 0);
                acc[fi][fj] = __builtin_amdgcn_mfma_f32_16x16x32_bf16(a_h[fi], b_l[fj], acc[fi][fj], 0, 0, 0);
            }
    }

#pragma unroll
    for (int fi = 0; fi < 4; ++fi) {
#pragma unroll
        for (int r = 0; r < 4; ++r) {
            float s = 0.f;
#pragma unroll
            for (int fj = 0; fj < 4; ++fj) {
                const float hval = acc[fi][fj][r] + b1r[fj];
                s = fmaf(w2r[fj], fmaxf(hval, 0.f), s);
            }
            s += __shfl_xor(s, 1);
            s += __shfl_xor(s, 2);
            s += __shfl_xor(s, 4);
            s += __shfl_xor(s, 8);
            if (l15 == 0)
                atomicAdd(&s2ws[tok0 + wr * 64 + fi * 16 + quad * 4 + r], s);
        }
    }
}

// ---------------------------------------------------------------------------
// Kernel 3: per-token routing (R3 version, proven fast)
// ---------------------------------------------------------------------------
__global__ __launch_bounds__(64) void route_kernel(
    const float* __restrict__ logits, const float* __restrict__ s2ws,
    const float* __restrict__ B2, float* __restrict__ sel,
    float* __restrict__ wts, float* __restrict__ load_sum,
    float* __restrict__ ent_sum)
{
    const int lane = threadIdx.x;
    const int tok  = blockIdx.x * 64 + lane;

    float r[64];
    const float* lr = logits + (size_t)tok * NEXP;
#pragma unroll
    for (int e4 = 0; e4 < 16; e4++) {
        float4 v = *(const float4*)(lr + e4 * 4);
        r[e4 * 4 + 0] = v.x; r[e4 * 4 + 1] = v.y;
        r[e4 * 4 + 2] = v.z; r[e4 * 4 + 3] = v.w;
    }

    float v0 = -1e30f, v1 = -1e30f, v2 = -1e30f, v3 = -1e30f;
    int   i0 = 0, i1 = 0, i2 = 0, i3 = 0;
#pragma unroll
    for (int e = 0; e < 64; e++) {
        const float v = r[e];
        if (v > v3) {
            if (v > v2) {
                if (v > v1) {
                    if (v > v0) { v3=v2;i3=i2; v2=v1;i2=i1; v1=v0;i1=i0; v0=v;i0=e; }
                    else        { v3=v2;i3=i2; v2=v1;i2=i1; v1=v;i1=e; }
                } else          { v3=v2;i3=i2; v2=v;i2=e; }
            } else              { v3=v;i3=e; }
        }
    }

    const float s2 = s2ws[tok] + B2[0];
    const bool k4 = (s2 > 0.f);

    float w0, w1v, w2v, w3v;
    int   s1i, s2i, s3i;
    if (k4) {
        const float e0 = expf(v0 - v0), e1 = expf(v1 - v0);
        const float e2 = expf(v2 - v0), e3 = expf(v3 - v0);
        const float inv4 = 1.f / (e0 + e1 + e2 + e3);
        w0 = e0 * inv4; w1v = e1 * inv4; w2v = e2 * inv4; w3v = e3 * inv4;
        s1i = i1; s2i = i2; s3i = i3;
    } else {
        w0 = 1.f; w1v = 0.f; w2v = 0.f; w3v = 0.f;
        s1i = 0; s2i = 0; s3i = 0;
    }
    {
        float4 sv = {(float)i0, (float)s1i, (float)s2i, (float)s3i};
        float4 wv = {w0, w1v, w2v, w3v};
        *(float4*)(sel + (size_t)tok * 4) = sv;
        *(float4*)(wts + (size_t)tok * 4) = wv;
    }

    const float mx = v0;
    float S = 0.f, pz = 0.f;
#pragma unroll
    for (int e = 0; e < 64; e++) {
        const float z = r[e] - mx;
        const float t = expf(z);
        S += t; pz = fmaf(t, z, pz);
        r[e] = t;
    }
    const float inv = 1.f / S;
    float ent = logf(S) - pz * inv;

    float myload = 0.f;
#pragma unroll
    for (int e = 0; e < 64; e++) {
        float s = r[e] * inv;
        s += __shfl_xor(s, 1);
        s += __shfl_xor(s, 2);
        s += __shfl_xor(s, 4);
        s += __shfl_xor(s, 8);
        s += __shfl_xor(s, 16);
        s += __shfl_xor(s, 32);
        if (lane == e) myload = s;
    }
    atomicAdd(&load_sum[lane], myload);

    ent += __shfl_xor(ent, 1);
    ent += __shfl_xor(ent, 2);
    ent += __shfl_xor(ent, 4);
    ent += __shfl_xor(ent, 8);
    ent += __shfl_xor(ent, 16);
    ent += __shfl_xor(ent, 32);
    if (lane == 0) atomicAdd(ent_sum, ent);
}

__global__ void finalize_kernel(const float* __restrict__ load_sum,
                                const float* __restrict__ ent_sum,
                                float* __restrict__ out_scal)
{
    const int lane = threadIdx.x;
    const float le = load_sum[lane] * (1.f / (float)NTOK);
    float s = le;
#pragma unroll
    for (int o = 32; o >= 1; o >>= 1) s += __shfl_xor(s, o);
    const float mean = s * (1.f / 64.f);
    const float d = le - mean;
    float v = d * d;
#pragma unroll
    for (int o = 32; o >= 1; o >>= 1) v += __shfl_xor(v, o);
    if (lane == 0) {
        out_scal[0] = v * (1.f / 63.f);
        out_scal[1] = ent_sum[0] * (1.f / (float)NTOK);
    }
}

extern "C" void kernel_launch(void* const* d_in, const int* in_sizes, int n_in,
                              void* d_out, int out_size, void* d_ws, size_t ws_size,
                              hipStream_t stream) {
    const float* X  = (const float*)d_in[0];
    const float* RW = (const float*)d_in[1];
    const float* W1 = (const float*)d_in[2];
    const float* B1 = (const float*)d_in[3];
    const float* W2 = (const float*)d_in[4];
    const float* B2 = (const float*)d_in[5];

    float* out    = (float*)d_out;
    float* logits = out;
    float* sel    = out + (size_t)NTOK * NEXP;
    float* wts    = sel + (size_t)NTOK * 4;
    float* scal   = wts + (size_t)NTOK * 4;

    float* s2ws     = (float*)d_ws;
    float* load_sum = s2ws + NTOK;
    float* ent_sum  = load_sum + 64;
    ushort* W1h = (ushort*)(s2ws + NTOK + 256);
    ushort* W1l = W1h + (size_t)H4 * HID;

    hipMemsetAsync(d_ws, 0, (size_t)(NTOK + 65) * sizeof(float), stream);

    prep_w1<<<256, 256, 0, stream>>>(W1, W1h, W1l);
    logits_gemm<<<NTOK / 64, 256, 0, stream>>>(X, RW, logits);
    pred_mfma<<<dim3(NTOK / 128, 2), 256, 0, stream>>>(X, W1h, W1l, B1, W2, s2ws);
    route_kernel<<<NTOK / 64, 64, 0, stream>>>(logits, s2ws, B2, sel, wts, load_sum, ent_sum);
    finalize_kernel<<<1, 64, 0, stream>>>(load_sum, ent_sum, scal);
}